// Round 1
// 319.685 us; speedup vs baseline: 1.1175x; 1.1175x over previous
//
#include <hip/hip_runtime.h>
#include <hip/hip_fp16.h>
#include <math.h>

#define H 512
#define W 512
#define S (H*W)
#define BS 16
#define CH 3
#define NP (BS*CH)

#define T     10   // Chebyshev steps, all fused in one kernel
#define R     56   // extended rows held per block
#define STRIP 36   // rows still correct after T steps: R - 2*T
#define RPW   7    // rows per wave (8 waves x 7 = 56)
#define NBX   15   // ceil(H / STRIP)

typedef unsigned int   uint_t;
typedef unsigned short ush;

struct F8 { float f[8]; };

__device__ __forceinline__ F8 unpk(uint4 r) {
  F8 o;
  float2 a = __half22float2(*(__half2*)&r.x); o.f[0]=a.x; o.f[1]=a.y;
  float2 b = __half22float2(*(__half2*)&r.y); o.f[2]=b.x; o.f[3]=b.y;
  float2 c = __half22float2(*(__half2*)&r.z); o.f[4]=c.x; o.f[5]=c.y;
  float2 d = __half22float2(*(__half2*)&r.w); o.f[6]=d.x; o.f[7]=d.y;
  return o;
}
__device__ __forceinline__ uint_t pk2(float a, float b) {
  __half2 h = __floats2half2_rn(a, b); return *(uint_t*)&h;
}
__device__ __forceinline__ uint4 pk8(const float* f) {
  return make_uint4(pk2(f[0],f[1]), pk2(f[2],f[3]), pk2(f[4],f[5]), pk2(f[6],f[7]));
}
__device__ __forceinline__ uint4 pkf8(float4 a, float4 b) {
  return make_uint4(pk2(a.x,a.y), pk2(a.z,a.w), pk2(b.x,b.y), pk2(b.z,b.w));
}
__device__ __forceinline__ float hi_h(uint_t u){ return __half22float2(*(__half2*)&u).y; }
__device__ __forceinline__ float lo_h(uint_t u){ return __half22float2(*(__half2*)&u).x; }

// All 10 Chebyshev steps fused via rectangle temporal blocking.
// Block: 512 thr (8 waves x 7 rows), holds R=56 rows of x in fp16 ping-pong
// LDS (116 KiB -> 1 block/CU). b, wc, wr stay packed-fp16 in VGPRs for the
// whole kernel (loaded fp32 once, converted inline -> no convert kernel, no
// workspace). Each step corrupts 1 row per side (out-of-tile neighbor = 0);
// after 10 steps the central STRIP=36 rows are exact and the final step
// writes them straight to global as fp32.
__global__ void __launch_bounds__(512, 2)
cheb_fused(const float* __restrict__ Bsrc, const float* __restrict__ WCs,
           const float* __restrict__ WRs, float* __restrict__ OUT)
{
  __shared__ __align__(16) ush xs[2][R+2][W];   // 2 x 58 x 512 fp16 = 116 KiB

  const int j  = blockIdx.y;                    // plane 0..47
  const int bb = j / CH;                        // batch
  const int y0 = (int)blockIdx.x * STRIP;       // first interior row
  const int ys = y0 - T;                        // first extended row
  const int tid = (int)threadIdx.x;
  const int wv = tid >> 6, lane = tid & 63;
  const uint4 zz = make_uint4(0,0,0,0);

  const float* bp = Bsrc + (size_t)j  * S;
  const float* wc = WCs  + (size_t)bb * (size_t)(H-1) * W;
  const float* wr = WRs  + (size_t)bb * (size_t)H * (W-1);

  // zero the 4 pad rows (row 0 and row R+1 of both buffers) — they stay 0
  if (tid < 256) {
    const int rq = tid >> 6, u = tid & 63;
    *(uint4*)&xs[rq >> 1][(rq & 1) ? (R+1) : 0][u*8] = zz;
  }

  // ---- init: load fp32 inputs once, pack to fp16 regs; x0 = fp16(b) -> LDS
  const int rb = wv * RPW;
  uint4 breg[RPW], wcreg[RPW], wrreg[RPW];
  uint4 wcpre = zz;
#pragma unroll
  for (int i = 0; i < RPW; ++i) {
    const int y = ys + rb + i;
    uint4 bpk = zz, wcpk = zz, wrpk = zz;
    if ((unsigned)y < H) {
      const float* p = bp + (size_t)y*W + lane*8;
      bpk = pkf8(*(const float4*)p, *(const float4*)(p + 4));
      // wr rows have stride 511 floats (unaligned) -> scalar loads; col 511 = 0
      const float* q = wr + (size_t)y*(W-1) + lane*8;
      const float a0=q[0],a1=q[1],a2=q[2],a3=q[3],a4=q[4],a5=q[5],a6=q[6];
      const float a7 = (lane < 63) ? q[7] : 0.f;
      wrpk = make_uint4(pk2(a0,a1), pk2(a2,a3), pk2(a4,a5), pk2(a6,a7));
    }
    if ((unsigned)y < (H-1)) {
      const float* p = wc + (size_t)y*W + lane*8;
      wcpk = pkf8(*(const float4*)p, *(const float4*)(p + 4));
    }
    breg[i] = bpk; wcreg[i] = wcpk; wrreg[i] = wrpk;
    *(uint4*)&xs[0][rb + i + 1][lane*8] = bpk;
  }
  { // up-weight for the wave's first row: wc[y_first - 1]
    const int y = ys + rb - 1;
    if ((unsigned)y < (H-1)) {
      const float* p = wc + (size_t)y*W + lane*8;
      wcpre = pkf8(*(const float4*)p, *(const float4*)(p + 4));
    }
  }
  __syncthreads();

  // ---- 10 steps, 1 barrier each. t-loop kept rolled (I-cache), i-loop
  // fully unrolled (static reg-array indices, rolling x/wc reuse).
  int cur = 0;
#pragma unroll 1
  for (int t = 0; t < T; ++t) {
    // Lebedev pair order (1,10),(2,9),... identical to prior kernel
    const int kk = (t & 1) ? (10 - (t >> 1)) : (1 + (t >> 1));
    const float tau = 1.f /
        (5.f + 4.f * __cosf(0.15707963267948966f * (float)(2*kk - 1)));
    const ush (*cb)[W] = xs[cur];
    ush (*nb)[W] = xs[cur ^ 1];
    const bool last = (t == T-1);

    uint4 xc_pk = *(const uint4*)&cb[rb + 1][lane*8];
    F8 xu = unpk(*(const uint4*)&cb[rb][lane*8]);
    F8 xc = unpk(xc_pk);
    F8 wu = unpk(wcpre);
#pragma unroll
    for (int i = 0; i < RPW; ++i) {
      const uint4 xd_pk = *(const uint4*)&cb[rb + i + 2][lane*8];
      const F8 xd = unpk(xd_pk);
      const F8 wd = unpk(wcreg[i]);
      const F8 w  = unpk(wrreg[i]);
      const F8 b  = unpk(breg[i]);
      const uint_t ux  = (uint_t)__shfl_up((int)xc_pk.w, 1);
      const float xl0  = lane ? hi_h(ux) : 0.f;
      const uint_t dxp = (uint_t)__shfl_down((int)xc_pk.x, 1);
      const float xr7  = (lane < 63) ? lo_h(dxp) : 0.f;
      const uint_t uwp = (uint_t)__shfl_up((int)wrreg[i].w, 1);
      const float wlm  = lane ? hi_h(uwp) : 0.f;
      float o[8];
#pragma unroll
      for (int p = 0; p < 8; ++p) {
        const float wl  = p ? w.f[p-1] : wlm;
        const float wrv = w.f[p];
        const float xl  = p ? xc.f[p-1] : xl0;
        const float xr  = (p < 7) ? xc.f[p+1] : xr7;
        const float kv  = 1.f + wu.f[p] + wd.f[p] + wl + wrv;
        const float av  = kv * xc.f[p] - wu.f[p]*xu.f[p] - wd.f[p]*xd.f[p]
                          - wl*xl - wrv*xr;
        o[p] = xc.f[p] + tau * (b.f[p] - av);
      }
      if (!last) {
        *(uint4*)&nb[rb + i + 1][lane*8] = pk8(o);
      } else {
        const int y = ys + rb + i;
        if (y >= y0 && y < y0 + STRIP && y < H) {
          float* dst = OUT + (size_t)j*S + (size_t)y*W + lane*8;
          *(float4*)dst       = make_float4(o[0],o[1],o[2],o[3]);
          *(float4*)(dst + 4) = make_float4(o[4],o[5],o[6],o[7]);
        }
      }
      // roll: down(i) becomes center(i+1); wc[i] becomes up-weight(i+1)
      xu = xc; xc = xd; xc_pk = xd_pk; wu = wd;
    }
    cur ^= 1;
    if (t < T-1) __syncthreads();
  }
}

extern "C" void kernel_launch(void* const* d_in, const int* in_sizes, int n_in,
                              void* d_out, int out_size, void* d_ws, size_t ws_size,
                              hipStream_t stream) {
  (void)in_sizes; (void)n_in; (void)out_size; (void)d_ws; (void)ws_size;
  const float* Bp = (const float*)d_in[0];
  const float* WC = (const float*)d_in[1];
  const float* WR = (const float*)d_in[2];
  dim3 grid(NBX, NP), block(512);
  cheb_fused<<<grid, block, 0, stream>>>(Bp, WC, WR, (float*)d_out);
}